// Round 1
// baseline (622.873 us; speedup 1.0000x reference)
//
#include <hip/hip_runtime.h>

#define N_TOK 2048
#define HD    1024
#define FD    4096
#define NE    8

typedef __attribute__((ext_vector_type(8))) short short8;
typedef __attribute__((ext_vector_type(4))) float floatx4;

// ---------- helpers ----------
__device__ __forceinline__ unsigned short f2bf(float f) {
  unsigned int u = __float_as_uint(f);
  u += 0x7fffu + ((u >> 16) & 1u);   // RNE
  return (unsigned short)(u >> 16);
}

__device__ __forceinline__ void gl2lds16(const unsigned short* g, unsigned short* l) {
  __builtin_amdgcn_global_load_lds(
      (const __attribute__((address_space(1))) unsigned int*)g,
      (__attribute__((address_space(3))) unsigned int*)l, 16, 0, 0);
}

__device__ __forceinline__ float gelu_tanh(float x) {
  // JAX default: approximate=True (tanh form)
  float t = 0.7978845608028654f * x * (1.0f + 0.044715f * x * x);
  return 0.5f * x * (1.0f + tanhf(t));
}

// ---------- gating: logits[e][n] = dot(x[n], Wg[e]) ----------
__global__ void k_gating(const float* __restrict__ x, const float* __restrict__ wg,
                         float* __restrict__ p) {
  int wave = threadIdx.x >> 6;
  int lane = threadIdx.x & 63;
  int n = blockIdx.x * 4 + wave;          // grid 512 * 4 waves = 2048
  const float* xr = x + (size_t)n * HD;
  for (int e = 0; e < NE; ++e) {
    const float* wr = wg + (size_t)e * HD;
    float s = 0.f;
    for (int i = lane; i < HD; i += 64) s += xr[i] * wr[i];
    for (int o = 32; o > 0; o >>= 1) s += __shfl_xor(s, o, 64);
    if (lane == 0) p[e * N_TOK + n] = s;
  }
}

// ---------- softmax over axis=0 (per expert column) ----------
__global__ void k_softmax(float* __restrict__ p) {
  int e = blockIdx.x;
  float* col = p + e * N_TOK;
  __shared__ float red[256];
  int t = threadIdx.x;
  float m = -1e30f;
  for (int i = t; i < N_TOK; i += 256) m = fmaxf(m, col[i]);
  red[t] = m; __syncthreads();
  for (int s = 128; s > 0; s >>= 1) { if (t < s) red[t] = fmaxf(red[t], red[t + s]); __syncthreads(); }
  m = red[0]; __syncthreads();
  float sum = 0.f;
  for (int i = t; i < N_TOK; i += 256) { float v = expf(col[i] - m); col[i] = v; sum += v; }
  red[t] = sum; __syncthreads();
  for (int s = 128; s > 0; s >>= 1) { if (t < s) red[t] += red[t + s]; __syncthreads(); }
  float inv = 1.0f / red[0];
  for (int i = t; i < N_TOK; i += 256) col[i] *= inv;
}

// ---------- routing: per-expert token lists + normalized weights ----------
__global__ void k_route(const int* __restrict__ mp, const float* __restrict__ p,
                        int* __restrict__ cnt, int* __restrict__ idxl, float* __restrict__ wtl) {
  int n = blockIdx.x * 256 + threadIdx.x;
  if (n >= N_TOK) return;
  int m0 = mp[n * 2 + 0], m1 = mp[n * 2 + 1];
  if (m0 == m1) {
    int s = atomicAdd(&cnt[m0], 1);
    idxl[m0 * N_TOK + s] = n; wtl[m0 * N_TOK + s] = 1.0f;
  } else {
    float p0 = p[m0 * N_TOK + n], p1 = p[m1 * N_TOK + n];
    float inv = 1.0f / (p0 + p1);
    int s0 = atomicAdd(&cnt[m0], 1);
    idxl[m0 * N_TOK + s0] = n; wtl[m0 * N_TOK + s0] = p0 * inv;
    int s1 = atomicAdd(&cnt[m1], 1);
    idxl[m1 * N_TOK + s1] = n; wtl[m1 * N_TOK + s1] = p1 * inv;
  }
}

// ---------- padded arena offsets ----------
__global__ void k_offsets(const int* __restrict__ cnt, int* __restrict__ poff) {
  if (threadIdx.x == 0 && blockIdx.x == 0) {
    int o = 0;
    for (int e = 0; e < NE; ++e) { poff[e] = o; o += (cnt[e] + 127) & ~127; }
    poff[NE] = o;
  }
}

// ---------- gather x rows -> bf16 arena (zero-padded to 128) ----------
__global__ void k_gather(const float* __restrict__ x, const int* __restrict__ cnt,
                         const int* __restrict__ poff, const int* __restrict__ idxl,
                         unsigned short* __restrict__ xg) {
  int e = blockIdx.y;
  int r = blockIdx.x;
  int c = cnt[e];
  int pc = (c + 127) & ~127;
  if (r >= pc) return;
  unsigned short* dst = xg + ((size_t)poff[e] + r) * HD;
  int t = threadIdx.x;  // 128 threads, 8 elems each
  union { unsigned short us[8]; uint4 v; } o;
  if (r < c) {
    const float* src = x + (size_t)idxl[e * N_TOK + r] * HD;
    float4 f0 = ((const float4*)src)[t * 2];
    float4 f1 = ((const float4*)src)[t * 2 + 1];
    o.us[0] = f2bf(f0.x); o.us[1] = f2bf(f0.y); o.us[2] = f2bf(f0.z); o.us[3] = f2bf(f0.w);
    o.us[4] = f2bf(f1.x); o.us[5] = f2bf(f1.y); o.us[6] = f2bf(f1.z); o.us[7] = f2bf(f1.w);
  } else {
    o.v.x = 0u; o.v.y = 0u; o.v.z = 0u; o.v.w = 0u;
  }
  ((uint4*)dst)[t] = o.v;
}

// ---------- transpose + fp32->bf16: src (E,rows,cols) -> dst (E,cols,rows) ----------
__global__ void k_transcvt(const float* __restrict__ src, unsigned short* __restrict__ dst,
                           int rows, int cols) {
  __shared__ float tile[32][33];
  const size_t base = (size_t)blockIdx.z * rows * cols;
  int c0 = blockIdx.x * 32, r0 = blockIdx.y * 32;
  int tx = threadIdx.x, ty = threadIdx.y;  // (32,8)
  #pragma unroll
  for (int i = 0; i < 32; i += 8)
    tile[ty + i][tx] = src[base + (size_t)(r0 + ty + i) * cols + c0 + tx];
  __syncthreads();
  #pragma unroll
  for (int i = 0; i < 32; i += 8)
    dst[base + (size_t)(c0 + ty + i) * rows + r0 + tx] = f2bf(tile[tx][ty + i]);
}

// ---------- GEMM1: h = gelu(xg @ W1[e] + b1[e])  (K=1024) ----------
__global__ __launch_bounds__(256) void k_gemm1(
    const unsigned short* __restrict__ xg, const unsigned short* __restrict__ w1t,
    const float* __restrict__ b1, const int* __restrict__ cnt, const int* __restrict__ poff,
    unsigned short* __restrict__ h) {
  const int e = blockIdx.z;
  const int c = cnt[e];
  const int mbase = blockIdx.y * 128;
  if (mbase >= c) return;
  const int nbase = blockIdx.x * 128;
  const unsigned short* A = xg + ((size_t)poff[e] + mbase) * HD;
  const unsigned short* B = w1t + ((size_t)e * FD + nbase) * HD;

  __shared__ unsigned short As[128 * 32];
  __shared__ unsigned short Bs[128 * 32];

  const int tid = threadIdx.x;
  const int wave = tid >> 6, lane = tid & 63;
  const int quad = lane >> 4, lrow = lane & 15;
  const int wm = (wave >> 1) * 64, wn = (wave & 1) * 64;

  floatx4 acc[4][4];
  #pragma unroll
  for (int i = 0; i < 4; ++i)
    #pragma unroll
    for (int j = 0; j < 4; ++j) acc[i][j] = (floatx4){0.f, 0.f, 0.f, 0.f};

  const int r0c = tid >> 2,          k0c = (tid & 3) * 8;
  const int r1c = (256 + tid) >> 2,  k1c = ((256 + tid) & 3) * 8;

  for (int kt = 0; kt < HD / 32; ++kt) {
    __syncthreads();
    const unsigned short* ga = A + kt * 32;
    const unsigned short* gb = B + kt * 32;
    gl2lds16(ga + (size_t)r0c * HD + k0c, As + (size_t)(wave * 64) * 8);
    gl2lds16(ga + (size_t)r1c * HD + k1c, As + (size_t)(256 + wave * 64) * 8);
    gl2lds16(gb + (size_t)r0c * HD + k0c, Bs + (size_t)(wave * 64) * 8);
    gl2lds16(gb + (size_t)r1c * HD + k1c, Bs + (size_t)(256 + wave * 64) * 8);
    __syncthreads();
    short8 aF[4], bF[4];
    #pragma unroll
    for (int i = 0; i < 4; ++i) aF[i] = *(const short8*)(As + (wm + i * 16 + lrow) * 32 + quad * 8);
    #pragma unroll
    for (int j = 0; j < 4; ++j) bF[j] = *(const short8*)(Bs + (wn + j * 16 + lrow) * 32 + quad * 8);
    #pragma unroll
    for (int i = 0; i < 4; ++i)
      #pragma unroll
      for (int j = 0; j < 4; ++j)
        acc[i][j] = __builtin_amdgcn_mfma_f32_16x16x32_bf16(aF[i], bF[j], acc[i][j], 0, 0, 0);
  }

  const size_t hrow0 = (size_t)poff[e] + mbase;
  #pragma unroll
  for (int i = 0; i < 4; ++i) {
    #pragma unroll
    for (int rr = 0; rr < 4; ++rr) {
      int row = wm + i * 16 + quad * 4 + rr;
      unsigned short* hr = h + (hrow0 + row) * FD + nbase;
      #pragma unroll
      for (int j = 0; j < 4; ++j) {
        int col = wn + j * 16 + lrow;
        float v = acc[i][j][rr] + b1[e * FD + nbase + col];
        hr[col] = f2bf(gelu_tanh(v));
      }
    }
  }
}

// ---------- GEMM2: out[tok] += w * (h @ W2[e] + b2[e])  (K=4096) ----------
__global__ __launch_bounds__(256) void k_gemm2(
    const unsigned short* __restrict__ h, const unsigned short* __restrict__ w2t,
    const float* __restrict__ b2, const int* __restrict__ cnt, const int* __restrict__ poff,
    const int* __restrict__ idxl, const float* __restrict__ wtl, float* __restrict__ out) {
  const int e = blockIdx.z;
  const int c = cnt[e];
  const int mbase = blockIdx.y * 128;
  if (mbase >= c) return;
  const int nbase = blockIdx.x * 128;
  const unsigned short* A = h + ((size_t)poff[e] + mbase) * FD;
  const unsigned short* B = w2t + ((size_t)e * HD + nbase) * FD;

  __shared__ unsigned short As[128 * 32];
  __shared__ unsigned short Bs[128 * 32];

  const int tid = threadIdx.x;
  const int wave = tid >> 6, lane = tid & 63;
  const int quad = lane >> 4, lrow = lane & 15;
  const int wm = (wave >> 1) * 64, wn = (wave & 1) * 64;

  floatx4 acc[4][4];
  #pragma unroll
  for (int i = 0; i < 4; ++i)
    #pragma unroll
    for (int j = 0; j < 4; ++j) acc[i][j] = (floatx4){0.f, 0.f, 0.f, 0.f};

  const int r0c = tid >> 2,          k0c = (tid & 3) * 8;
  const int r1c = (256 + tid) >> 2,  k1c = ((256 + tid) & 3) * 8;

  for (int kt = 0; kt < FD / 32; ++kt) {
    __syncthreads();
    const unsigned short* ga = A + kt * 32;
    const unsigned short* gb = B + kt * 32;
    gl2lds16(ga + (size_t)r0c * FD + k0c, As + (size_t)(wave * 64) * 8);
    gl2lds16(ga + (size_t)r1c * FD + k1c, As + (size_t)(256 + wave * 64) * 8);
    gl2lds16(gb + (size_t)r0c * FD + k0c, Bs + (size_t)(wave * 64) * 8);
    gl2lds16(gb + (size_t)r1c * FD + k1c, Bs + (size_t)(256 + wave * 64) * 8);
    __syncthreads();
    short8 aF[4], bF[4];
    #pragma unroll
    for (int i = 0; i < 4; ++i) aF[i] = *(const short8*)(As + (wm + i * 16 + lrow) * 32 + quad * 8);
    #pragma unroll
    for (int j = 0; j < 4; ++j) bF[j] = *(const short8*)(Bs + (wn + j * 16 + lrow) * 32 + quad * 8);
    #pragma unroll
    for (int i = 0; i < 4; ++i)
      #pragma unroll
      for (int j = 0; j < 4; ++j)
        acc[i][j] = __builtin_amdgcn_mfma_f32_16x16x32_bf16(aF[i], bF[j], acc[i][j], 0, 0, 0);
  }

  #pragma unroll
  for (int i = 0; i < 4; ++i) {
    #pragma unroll
    for (int rr = 0; rr < 4; ++rr) {
      int row = wm + i * 16 + quad * 4 + rr;
      int gr = mbase + row;
      if (gr < c) {
        int tok = idxl[e * N_TOK + gr];
        float wgt = wtl[e * N_TOK + gr];
        float* orow = out + (size_t)tok * HD + nbase;
        #pragma unroll
        for (int j = 0; j < 4; ++j) {
          int col = wn + j * 16 + lrow;
          atomicAdd(orow + col, wgt * (acc[i][j][rr] + b2[e * HD + nbase + col]));
        }
      }
    }
  }
}

// ---------- launch ----------
extern "C" void kernel_launch(void* const* d_in, const int* in_sizes, int n_in,
                              void* d_out, int out_size, void* d_ws, size_t ws_size,
                              hipStream_t stream) {
  const float* x  = (const float*)d_in[0];
  const int*   mp = (const int*)d_in[1];
  const float* wg = (const float*)d_in[2];
  const float* w1 = (const float*)d_in[3];
  const float* b1 = (const float*)d_in[4];
  const float* w2 = (const float*)d_in[5];
  const float* b2 = (const float*)d_in[6];
  float* out = (float*)d_out;
  char* ws = (char*)d_ws;

  // workspace layout (bytes)
  float* p    = (float*)(ws + 0);          // 8*2048*4 = 65536
  int*   cnt  = (int*)(ws + 65536);        // 32
  int*   poff = (int*)(ws + 65792);        // 36
  int*   idxl = (int*)(ws + 66048);        // 65536
  float* wtl  = (float*)(ws + 131584);     // 65536
  unsigned short* w1t = (unsigned short*)(ws + 197120);                          // 67.1 MB
  unsigned short* w2t = (unsigned short*)(ws + 197120 + 67108864);               // 67.1 MB
  unsigned short* xg  = (unsigned short*)(ws + 197120 + 2 * 67108864);           // 10.5 MB
  unsigned short* h   = (unsigned short*)(ws + 197120 + 2 * 67108864 + 10485760);// 41.9 MB

  hipMemsetAsync(cnt, 0, 32, stream);
  hipMemsetAsync(d_out, 0, (size_t)out_size * 4, stream);

  k_gating<<<512, 256, 0, stream>>>(x, wg, p);
  k_softmax<<<NE, 256, 0, stream>>>(p);
  k_route<<<NE, 256, 0, stream>>>(mp, p, cnt, idxl, wtl);
  k_offsets<<<1, 64, 0, stream>>>(cnt, poff);
  k_transcvt<<<dim3(FD / 32, HD / 32, NE), dim3(32, 8), 0, stream>>>(w1, w1t, HD, FD);
  k_transcvt<<<dim3(HD / 32, FD / 32, NE), dim3(32, 8), 0, stream>>>(w2, w2t, FD, HD);
  k_gather<<<dim3(N_TOK, NE), 128, 0, stream>>>(x, cnt, poff, idxl, xg);
  k_gemm1<<<dim3(FD / 128, 16, NE), 256, 0, stream>>>(xg, w1t, b1, cnt, poff, h);
  k_gemm2<<<dim3(HD / 128, 16, NE), 256, 0, stream>>>(h, w2t, b2, cnt, poff, idxl, wtl, out);
}

// Round 2
// 596.787 us; speedup vs baseline: 1.0437x; 1.0437x over previous
//
#include <hip/hip_runtime.h>

#define N_TOK 2048
#define HD    1024
#define FD    4096
#define NE    8
#define SPLITK 4

typedef __attribute__((ext_vector_type(8))) short short8;
typedef __attribute__((ext_vector_type(4))) float floatx4;

// ---------- helpers ----------
__device__ __forceinline__ unsigned short f2bf(float f) {
  unsigned int u = __float_as_uint(f);
  u += 0x7fffu + ((u >> 16) & 1u);   // RNE
  return (unsigned short)(u >> 16);
}

__device__ __forceinline__ void gl2lds16(const unsigned short* g, unsigned short* l) {
  __builtin_amdgcn_global_load_lds(
      (const __attribute__((address_space(1))) unsigned int*)g,
      (__attribute__((address_space(3))) unsigned int*)l, 16, 0, 0);
}

__device__ __forceinline__ float gelu_tanh(float x) {
  float t = 0.7978845608028654f * x * (1.0f + 0.044715f * x * x);
  return 0.5f * x * (1.0f + tanhf(t));
}

// ---------- gating: logits[e][n] = dot(x[n], Wg[e]) ----------
__global__ void k_gating(const float* __restrict__ x, const float* __restrict__ wg,
                         float* __restrict__ p) {
  int wave = threadIdx.x >> 6;
  int lane = threadIdx.x & 63;
  int n = blockIdx.x * 4 + wave;
  const float* xr = x + (size_t)n * HD;
  for (int e = 0; e < NE; ++e) {
    const float* wr = wg + (size_t)e * HD;
    float s = 0.f;
    for (int i = lane; i < HD; i += 64) s += xr[i] * wr[i];
    for (int o = 32; o > 0; o >>= 1) s += __shfl_xor(s, o, 64);
    if (lane == 0) p[e * N_TOK + n] = s;
  }
}

// ---------- softmax over axis=0 (per expert column) ----------
__global__ void k_softmax(float* __restrict__ p) {
  int e = blockIdx.x;
  float* col = p + e * N_TOK;
  __shared__ float red[256];
  int t = threadIdx.x;
  float m = -1e30f;
  for (int i = t; i < N_TOK; i += 256) m = fmaxf(m, col[i]);
  red[t] = m; __syncthreads();
  for (int s = 128; s > 0; s >>= 1) { if (t < s) red[t] = fmaxf(red[t], red[t + s]); __syncthreads(); }
  m = red[0]; __syncthreads();
  float sum = 0.f;
  for (int i = t; i < N_TOK; i += 256) { float v = expf(col[i] - m); col[i] = v; sum += v; }
  red[t] = sum; __syncthreads();
  for (int s = 128; s > 0; s >>= 1) { if (t < s) red[t] += red[t + s]; __syncthreads(); }
  float inv = 1.0f / red[0];
  for (int i = t; i < N_TOK; i += 256) col[i] *= inv;
}

// ---------- routing ----------
__global__ void k_route(const int* __restrict__ mp, const float* __restrict__ p,
                        int* __restrict__ cnt, int* __restrict__ idxl, float* __restrict__ wtl) {
  int n = blockIdx.x * 256 + threadIdx.x;
  if (n >= N_TOK) return;
  int m0 = mp[n * 2 + 0], m1 = mp[n * 2 + 1];
  if (m0 == m1) {
    int s = atomicAdd(&cnt[m0], 1);
    idxl[m0 * N_TOK + s] = n; wtl[m0 * N_TOK + s] = 1.0f;
  } else {
    float p0 = p[m0 * N_TOK + n], p1 = p[m1 * N_TOK + n];
    float inv = 1.0f / (p0 + p1);
    int s0 = atomicAdd(&cnt[m0], 1);
    idxl[m0 * N_TOK + s0] = n; wtl[m0 * N_TOK + s0] = p0 * inv;
    int s1 = atomicAdd(&cnt[m1], 1);
    idxl[m1 * N_TOK + s1] = n; wtl[m1 * N_TOK + s1] = p1 * inv;
  }
}

// ---------- padded arena offsets ----------
__global__ void k_offsets(const int* __restrict__ cnt, int* __restrict__ poff) {
  if (threadIdx.x == 0 && blockIdx.x == 0) {
    int o = 0;
    for (int e = 0; e < NE; ++e) { poff[e] = o; o += (cnt[e] + 127) & ~127; }
    poff[NE] = o;
  }
}

// ---------- gather x rows -> bf16 arena ----------
__global__ void k_gather(const float* __restrict__ x, const int* __restrict__ cnt,
                         const int* __restrict__ poff, const int* __restrict__ idxl,
                         unsigned short* __restrict__ xg) {
  int e = blockIdx.y;
  int r = blockIdx.x;
  int c = cnt[e];
  int pc = (c + 127) & ~127;
  if (r >= pc) return;
  unsigned short* dst = xg + ((size_t)poff[e] + r) * HD;
  int t = threadIdx.x;
  union { unsigned short us[8]; uint4 v; } o;
  if (r < c) {
    const float* src = x + (size_t)idxl[e * N_TOK + r] * HD;
    float4 f0 = ((const float4*)src)[t * 2];
    float4 f1 = ((const float4*)src)[t * 2 + 1];
    o.us[0] = f2bf(f0.x); o.us[1] = f2bf(f0.y); o.us[2] = f2bf(f0.z); o.us[3] = f2bf(f0.w);
    o.us[4] = f2bf(f1.x); o.us[5] = f2bf(f1.y); o.us[6] = f2bf(f1.z); o.us[7] = f2bf(f1.w);
  } else {
    o.v.x = 0u; o.v.y = 0u; o.v.z = 0u; o.v.w = 0u;
  }
  ((uint4*)dst)[t] = o.v;
}

// ---------- transpose + fp32->bf16 (64x64 tiles, vectorized both sides) ----------
// src (E,rows,cols) fp32 -> dst (E,cols,rows) bf16
__global__ __launch_bounds__(256) void k_transcvt(const float* __restrict__ src,
                                                  unsigned short* __restrict__ dst,
                                                  int rows, int cols) {
  __shared__ float tile[64][65];
  const size_t base = (size_t)blockIdx.z * rows * cols;
  int c0 = blockIdx.x * 64, r0 = blockIdx.y * 64;
  int t = threadIdx.x;
  int lr = t >> 4;            // 0..15
  int lc = (t & 15) * 4;      // float col offset
  #pragma unroll
  for (int i = 0; i < 64; i += 16) {
    float4 v = *(const float4*)(src + base + (size_t)(r0 + lr + i) * cols + c0 + lc);
    tile[lr + i][lc] = v.x; tile[lr + i][lc + 1] = v.y;
    tile[lr + i][lc + 2] = v.z; tile[lr + i][lc + 3] = v.w;
  }
  __syncthreads();
  int oc = t >> 2;            // 0..63 : output row (= src col)
  int rseg = (t & 3) * 16;    // segment along r
  union { unsigned short us[16]; uint4 v[2]; } o;
  #pragma unroll
  for (int i = 0; i < 16; ++i) o.us[i] = f2bf(tile[rseg + i][oc]);
  unsigned short* d = dst + base + (size_t)(c0 + oc) * rows + r0 + rseg;
  ((uint4*)d)[0] = o.v[0];
  ((uint4*)d)[1] = o.v[1];
}

// ---------- GEMM1: h = gelu(xg @ W1[e] + b1[e])  (K=1024) ----------
__global__ __launch_bounds__(256) void k_gemm1(
    const unsigned short* __restrict__ xg, const unsigned short* __restrict__ w1t,
    const float* __restrict__ b1, const int* __restrict__ cnt, const int* __restrict__ poff,
    unsigned short* __restrict__ h) {
  const int e = blockIdx.z;
  const int c = cnt[e];
  const int mbase = blockIdx.y * 128;
  if (mbase >= c) return;
  const int nbase = blockIdx.x * 128;
  const unsigned short* A = xg + ((size_t)poff[e] + mbase) * HD;
  const unsigned short* B = w1t + ((size_t)e * FD + nbase) * HD;

  __shared__ unsigned short As[128 * 32];
  __shared__ unsigned short Bs[128 * 32];

  const int tid = threadIdx.x;
  const int wave = tid >> 6, lane = tid & 63;
  const int quad = lane >> 4, lrow = lane & 15;
  const int wm = (wave >> 1) * 64, wn = (wave & 1) * 64;

  floatx4 acc[4][4];
  #pragma unroll
  for (int i = 0; i < 4; ++i)
    #pragma unroll
    for (int j = 0; j < 4; ++j) acc[i][j] = (floatx4){0.f, 0.f, 0.f, 0.f};

  const int r0c = tid >> 2,          k0c = (tid & 3) * 8;
  const int r1c = (256 + tid) >> 2,  k1c = ((256 + tid) & 3) * 8;

  for (int kt = 0; kt < HD / 32; ++kt) {
    __syncthreads();
    const unsigned short* ga = A + kt * 32;
    const unsigned short* gb = B + kt * 32;
    gl2lds16(ga + (size_t)r0c * HD + k0c, As + (size_t)(wave * 64) * 8);
    gl2lds16(ga + (size_t)r1c * HD + k1c, As + (size_t)(256 + wave * 64) * 8);
    gl2lds16(gb + (size_t)r0c * HD + k0c, Bs + (size_t)(wave * 64) * 8);
    gl2lds16(gb + (size_t)r1c * HD + k1c, Bs + (size_t)(256 + wave * 64) * 8);
    __syncthreads();
    short8 aF[4], bF[4];
    #pragma unroll
    for (int i = 0; i < 4; ++i) aF[i] = *(const short8*)(As + (wm + i * 16 + lrow) * 32 + quad * 8);
    #pragma unroll
    for (int j = 0; j < 4; ++j) bF[j] = *(const short8*)(Bs + (wn + j * 16 + lrow) * 32 + quad * 8);
    #pragma unroll
    for (int i = 0; i < 4; ++i)
      #pragma unroll
      for (int j = 0; j < 4; ++j)
        acc[i][j] = __builtin_amdgcn_mfma_f32_16x16x32_bf16(aF[i], bF[j], acc[i][j], 0, 0, 0);
  }

  const size_t hrow0 = (size_t)poff[e] + mbase;
  #pragma unroll
  for (int i = 0; i < 4; ++i) {
    #pragma unroll
    for (int rr = 0; rr < 4; ++rr) {
      int row = wm + i * 16 + quad * 4 + rr;
      unsigned short* hr = h + (hrow0 + row) * FD + nbase;
      #pragma unroll
      for (int j = 0; j < 4; ++j) {
        int col = wn + j * 16 + lrow;
        float v = acc[i][j][rr] + b1[e * FD + nbase + col];
        hr[col] = f2bf(gelu_tanh(v));
      }
    }
  }
}

// ---------- GEMM2 (split-K x4): out[tok] += w * (h @ W2[e] + b2[e]) ----------
__global__ __launch_bounds__(256) void k_gemm2(
    const unsigned short* __restrict__ h, const unsigned short* __restrict__ w2t,
    const float* __restrict__ b2, const int* __restrict__ cnt, const int* __restrict__ poff,
    const int* __restrict__ idxl, const float* __restrict__ wtl, float* __restrict__ out) {
  const int ez = blockIdx.z;
  const int e = ez >> 2;            // SPLITK=4
  const int sk = ez & 3;
  const int c = cnt[e];
  const int mbase = blockIdx.y * 128;
  if (mbase >= c) return;
  const int nbase = blockIdx.x * 128;
  const int KC = FD / SPLITK;       // 1024
  const unsigned short* A = h + ((size_t)poff[e] + mbase) * FD + sk * KC;
  const unsigned short* B = w2t + ((size_t)e * HD + nbase) * FD + sk * KC;

  __shared__ unsigned short As[128 * 32];
  __shared__ unsigned short Bs[128 * 32];

  const int tid = threadIdx.x;
  const int wave = tid >> 6, lane = tid & 63;
  const int quad = lane >> 4, lrow = lane & 15;
  const int wm = (wave >> 1) * 64, wn = (wave & 1) * 64;

  floatx4 acc[4][4];
  #pragma unroll
  for (int i = 0; i < 4; ++i)
    #pragma unroll
    for (int j = 0; j < 4; ++j) acc[i][j] = (floatx4){0.f, 0.f, 0.f, 0.f};

  const int r0c = tid >> 2,          k0c = (tid & 3) * 8;
  const int r1c = (256 + tid) >> 2,  k1c = ((256 + tid) & 3) * 8;

  for (int kt = 0; kt < KC / 32; ++kt) {
    __syncthreads();
    const unsigned short* ga = A + kt * 32;
    const unsigned short* gb = B + kt * 32;
    gl2lds16(ga + (size_t)r0c * FD + k0c, As + (size_t)(wave * 64) * 8);
    gl2lds16(ga + (size_t)r1c * FD + k1c, As + (size_t)(256 + wave * 64) * 8);
    gl2lds16(gb + (size_t)r0c * FD + k0c, Bs + (size_t)(wave * 64) * 8);
    gl2lds16(gb + (size_t)r1c * FD + k1c, Bs + (size_t)(256 + wave * 64) * 8);
    __syncthreads();
    short8 aF[4], bF[4];
    #pragma unroll
    for (int i = 0; i < 4; ++i) aF[i] = *(const short8*)(As + (wm + i * 16 + lrow) * 32 + quad * 8);
    #pragma unroll
    for (int j = 0; j < 4; ++j) bF[j] = *(const short8*)(Bs + (wn + j * 16 + lrow) * 32 + quad * 8);
    #pragma unroll
    for (int i = 0; i < 4; ++i)
      #pragma unroll
      for (int j = 0; j < 4; ++j)
        acc[i][j] = __builtin_amdgcn_mfma_f32_16x16x32_bf16(aF[i], bF[j], acc[i][j], 0, 0, 0);
  }

  #pragma unroll
  for (int i = 0; i < 4; ++i) {
    #pragma unroll
    for (int rr = 0; rr < 4; ++rr) {
      int row = wm + i * 16 + quad * 4 + rr;
      int gr = mbase + row;
      if (gr < c) {
        int tok = idxl[e * N_TOK + gr];
        float wgt = wtl[e * N_TOK + gr];
        float* orow = out + (size_t)tok * HD + nbase;
        #pragma unroll
        for (int j = 0; j < 4; ++j) {
          int col = wn + j * 16 + lrow;
          float bias = (sk == 0) ? b2[e * HD + nbase + col] : 0.0f;
          atomicAdd(orow + col, wgt * (acc[i][j][rr] + bias));
        }
      }
    }
  }
}

// ---------- launch ----------
extern "C" void kernel_launch(void* const* d_in, const int* in_sizes, int n_in,
                              void* d_out, int out_size, void* d_ws, size_t ws_size,
                              hipStream_t stream) {
  const float* x  = (const float*)d_in[0];
  const int*   mp = (const int*)d_in[1];
  const float* wg = (const float*)d_in[2];
  const float* w1 = (const float*)d_in[3];
  const float* b1 = (const float*)d_in[4];
  const float* w2 = (const float*)d_in[5];
  const float* b2 = (const float*)d_in[6];
  float* out = (float*)d_out;
  char* ws = (char*)d_ws;

  float* p    = (float*)(ws + 0);
  int*   cnt  = (int*)(ws + 65536);
  int*   poff = (int*)(ws + 65792);
  int*   idxl = (int*)(ws + 66048);
  float* wtl  = (float*)(ws + 131584);
  unsigned short* w1t = (unsigned short*)(ws + 197120);
  unsigned short* w2t = (unsigned short*)(ws + 197120 + 67108864);
  unsigned short* xg  = (unsigned short*)(ws + 197120 + 2 * 67108864);
  unsigned short* h   = (unsigned short*)(ws + 197120 + 2 * 67108864 + 10485760);

  hipMemsetAsync(cnt, 0, 32, stream);
  hipMemsetAsync(d_out, 0, (size_t)out_size * 4, stream);

  k_gating<<<512, 256, 0, stream>>>(x, wg, p);
  k_softmax<<<NE, 256, 0, stream>>>(p);
  k_route<<<NE, 256, 0, stream>>>(mp, p, cnt, idxl, wtl);
  k_offsets<<<1, 64, 0, stream>>>(cnt, poff);
  k_transcvt<<<dim3(FD / 64, HD / 64, NE), 256, 0, stream>>>(w1, w1t, HD, FD);
  k_transcvt<<<dim3(HD / 64, FD / 64, NE), 256, 0, stream>>>(w2, w2t, FD, HD);
  k_gather<<<dim3(N_TOK, NE), 128, 0, stream>>>(x, cnt, poff, idxl, xg);
  k_gemm1<<<dim3(FD / 128, 16, NE), 256, 0, stream>>>(xg, w1t, b1, cnt, poff, h);
  k_gemm2<<<dim3(HD / 128, 16, NE * SPLITK), 256, 0, stream>>>(h, w2t, b2, cnt, poff, idxl, wtl, out);
}

// Round 3
// 580.217 us; speedup vs baseline: 1.0735x; 1.0286x over previous
//
#include <hip/hip_runtime.h>

#define N_TOK 2048
#define HD    1024
#define FD    4096
#define NE    8
#define SK2   8          // gemm2 split-K factor

typedef __attribute__((ext_vector_type(8))) short short8;
typedef __attribute__((ext_vector_type(4))) float floatx4;

// ---------- helpers ----------
__device__ __forceinline__ unsigned short f2bf(float f) {
  unsigned int u = __float_as_uint(f);
  u += 0x7fffu + ((u >> 16) & 1u);   // RNE
  return (unsigned short)(u >> 16);
}

__device__ __forceinline__ void gl2lds16(const unsigned short* g, unsigned short* l) {
  __builtin_amdgcn_global_load_lds(
      (const __attribute__((address_space(1))) unsigned int*)g,
      (__attribute__((address_space(3))) unsigned int*)l, 16, 0, 0);
}

__device__ __forceinline__ float gelu_tanh(float x) {
  float t = 0.7978845608028654f * x * (1.0f + 0.044715f * x * x);
  return 0.5f * x * (1.0f + tanhf(t));
}

__device__ __forceinline__ int poff_of(const int* __restrict__ cnt, int e) {
  int o = 0;
  for (int i = 0; i < e; ++i) o += (cnt[i] + 127) & ~127;
  return o;
}

// ---------- gating: logits[e][n] = dot(x[n], Wg[e]) ----------
__global__ void k_gating(const float* __restrict__ x, const float* __restrict__ wg,
                         float* __restrict__ p) {
  int wave = threadIdx.x >> 6;
  int lane = threadIdx.x & 63;
  int n = blockIdx.x * 4 + wave;
  const float4* xr = (const float4*)(x + (size_t)n * HD);
  float4 xv[4];
  #pragma unroll
  for (int i = 0; i < 4; ++i) xv[i] = xr[lane + i * 64];
  for (int e = 0; e < NE; ++e) {
    const float4* wr = (const float4*)(wg + (size_t)e * HD);
    float s = 0.f;
    #pragma unroll
    for (int i = 0; i < 4; ++i) {
      float4 w4 = wr[lane + i * 64];
      s += xv[i].x * w4.x + xv[i].y * w4.y + xv[i].z * w4.z + xv[i].w * w4.w;
    }
    for (int o = 32; o > 0; o >>= 1) s += __shfl_xor(s, o, 64);
    if (lane == 0) p[e * N_TOK + n] = s;
  }
}

// ---------- softmax over axis=0 (per expert column) ----------
__global__ void k_softmax(float* __restrict__ p) {
  int e = blockIdx.x;
  float* col = p + e * N_TOK;
  __shared__ float red[256];
  int t = threadIdx.x;
  float m = -1e30f;
  for (int i = t; i < N_TOK; i += 256) m = fmaxf(m, col[i]);
  red[t] = m; __syncthreads();
  for (int s = 128; s > 0; s >>= 1) { if (t < s) red[t] = fmaxf(red[t], red[t + s]); __syncthreads(); }
  m = red[0]; __syncthreads();
  float sum = 0.f;
  for (int i = t; i < N_TOK; i += 256) { float v = expf(col[i] - m); col[i] = v; sum += v; }
  red[t] = sum; __syncthreads();
  for (int s = 128; s > 0; s >>= 1) { if (t < s) red[t] += red[t + s]; __syncthreads(); }
  float inv = 1.0f / red[0];
  for (int i = t; i < N_TOK; i += 256) col[i] *= inv;
}

// ---------- routing ----------
__global__ void k_route(const int* __restrict__ mp, const float* __restrict__ p,
                        int* __restrict__ cnt, int* __restrict__ idxl, float* __restrict__ wtl) {
  int n = blockIdx.x * 256 + threadIdx.x;
  if (n >= N_TOK) return;
  int m0 = mp[n * 2 + 0], m1 = mp[n * 2 + 1];
  if (m0 == m1) {
    int s = atomicAdd(&cnt[m0], 1);
    idxl[m0 * N_TOK + s] = n; wtl[m0 * N_TOK + s] = 1.0f;
  } else {
    float p0 = p[m0 * N_TOK + n], p1 = p[m1 * N_TOK + n];
    float inv = 1.0f / (p0 + p1);
    int s0 = atomicAdd(&cnt[m0], 1);
    idxl[m0 * N_TOK + s0] = n; wtl[m0 * N_TOK + s0] = p0 * inv;
    int s1 = atomicAdd(&cnt[m1], 1);
    idxl[m1 * N_TOK + s1] = n; wtl[m1 * N_TOK + s1] = p1 * inv;
  }
}

// ---------- gather x rows -> bf16 arena ----------
__global__ void k_gather(const float* __restrict__ x, const int* __restrict__ cnt,
                         const int* __restrict__ idxl, unsigned short* __restrict__ xg) {
  int e = blockIdx.y;
  int r = blockIdx.x;
  int c = cnt[e];
  int pc = (c + 127) & ~127;
  if (r >= pc) return;
  unsigned short* dst = xg + ((size_t)poff_of(cnt, e) + r) * HD;
  int t = threadIdx.x;
  union { unsigned short us[8]; uint4 v; } o;
  if (r < c) {
    const float* src = x + (size_t)idxl[e * N_TOK + r] * HD;
    float4 f0 = ((const float4*)src)[t * 2];
    float4 f1 = ((const float4*)src)[t * 2 + 1];
    o.us[0] = f2bf(f0.x); o.us[1] = f2bf(f0.y); o.us[2] = f2bf(f0.z); o.us[3] = f2bf(f0.w);
    o.us[4] = f2bf(f1.x); o.us[5] = f2bf(f1.y); o.us[6] = f2bf(f1.z); o.us[7] = f2bf(f1.w);
  } else {
    o.v.x = 0u; o.v.y = 0u; o.v.z = 0u; o.v.w = 0u;
  }
  ((uint4*)dst)[t] = o.v;
}

// ---------- merged transpose + fp32->bf16 for W1 and W2 ----------
// W1 (E,HD,FD) -> w1t (E,FD,HD);  W2 (E,FD,HD) -> w2t (E,HD,FD)
__global__ __launch_bounds__(256) void k_transcvt2(const float* __restrict__ w1,
                                                   unsigned short* __restrict__ w1t,
                                                   const float* __restrict__ w2,
                                                   unsigned short* __restrict__ w2t) {
  __shared__ float tile[64][65];
  int l = blockIdx.x;
  const float* src; unsigned short* dst; int rows, cols, bx, by, e;
  if (l < 8192) {        // W1: rows=HD, cols=FD
    src = w1; dst = w1t; rows = HD; cols = FD;
    bx = l & 63; by = (l >> 6) & 15; e = l >> 10;
  } else {               // W2: rows=FD, cols=HD
    int l2 = l - 8192;
    src = w2; dst = w2t; rows = FD; cols = HD;
    bx = l2 & 15; by = (l2 >> 4) & 63; e = l2 >> 10;
  }
  const size_t base = (size_t)e * rows * cols;
  int c0 = bx * 64, r0 = by * 64;
  int t = threadIdx.x;
  int lr = t >> 4;
  int lc = (t & 15) * 4;
  #pragma unroll
  for (int i = 0; i < 64; i += 16) {
    float4 v = *(const float4*)(src + base + (size_t)(r0 + lr + i) * cols + c0 + lc);
    tile[lr + i][lc] = v.x; tile[lr + i][lc + 1] = v.y;
    tile[lr + i][lc + 2] = v.z; tile[lr + i][lc + 3] = v.w;
  }
  __syncthreads();
  int oc = t >> 2;
  int rseg = (t & 3) * 16;
  union { unsigned short us[16]; uint4 v[2]; } o;
  #pragma unroll
  for (int i = 0; i < 16; ++i) o.us[i] = f2bf(tile[rseg + i][oc]);
  unsigned short* d = dst + base + (size_t)(c0 + oc) * rows + r0 + rseg;
  ((uint4*)d)[0] = o.v[0];
  ((uint4*)d)[1] = o.v[1];
}

// ---------- GEMM1: h = gelu(xg @ W1[e] + b1[e])  (K=1024, tile 64x128) ----------
// XCD supertile: linear = r + 8*m + 256*(e*4 + n/8); n = (q&3)*8 + r
// -> blocks sharing a B-tile (same e,n; 32 m's) are congruent mod 8 (same XCD).
__global__ __launch_bounds__(256) void k_gemm1(
    const unsigned short* __restrict__ xg, const unsigned short* __restrict__ w1t,
    const float* __restrict__ b1, const int* __restrict__ cnt,
    unsigned short* __restrict__ h) {
  const int l = blockIdx.x;
  const int r = l & 7;
  const int m = (l >> 3) & 31;
  const int q = l >> 8;
  const int e = q >> 2;
  const int n = ((q & 3) << 3) | r;

  const int c = cnt[e];
  const int mbase = m * 64;
  if (mbase >= c) return;
  const int nbase = n * 128;
  const int po = poff_of(cnt, e);
  const unsigned short* A = xg + ((size_t)po + mbase) * HD;
  const unsigned short* B = w1t + ((size_t)e * FD + nbase) * HD;

  __shared__ unsigned short As[64 * 32];
  __shared__ unsigned short Bs[128 * 32];

  const int tid = threadIdx.x;
  const int wave = tid >> 6, lane = tid & 63;
  const int quad = lane >> 4, lrow = lane & 15;
  const int wn = wave * 32;

  floatx4 acc[4][2];
  #pragma unroll
  for (int i = 0; i < 4; ++i)
    #pragma unroll
    for (int j = 0; j < 2; ++j) acc[i][j] = (floatx4){0.f, 0.f, 0.f, 0.f};

  const int rA = tid >> 2, kA = (tid & 3) * 8;               // 256 slots: A 64x4
  const int rB0 = tid >> 2, kB0 = (tid & 3) * 8;             // B slot 0
  const int rB1 = (256 + tid) >> 2, kB1 = ((256 + tid) & 3) * 8;

  for (int kt = 0; kt < HD / 32; ++kt) {
    __syncthreads();
    const unsigned short* ga = A + kt * 32;
    const unsigned short* gb = B + kt * 32;
    gl2lds16(ga + (size_t)rA * HD + kA, As + (size_t)(wave * 64) * 8);
    gl2lds16(gb + (size_t)rB0 * HD + kB0, Bs + (size_t)(wave * 64) * 8);
    gl2lds16(gb + (size_t)rB1 * HD + kB1, Bs + (size_t)(256 + wave * 64) * 8);
    __syncthreads();
    short8 aF[4], bF[2];
    #pragma unroll
    for (int i = 0; i < 4; ++i) aF[i] = *(const short8*)(As + (i * 16 + lrow) * 32 + quad * 8);
    #pragma unroll
    for (int j = 0; j < 2; ++j) bF[j] = *(const short8*)(Bs + (wn + j * 16 + lrow) * 32 + quad * 8);
    #pragma unroll
    for (int i = 0; i < 4; ++i)
      #pragma unroll
      for (int j = 0; j < 2; ++j)
        acc[i][j] = __builtin_amdgcn_mfma_f32_16x16x32_bf16(aF[i], bF[j], acc[i][j], 0, 0, 0);
  }

  const size_t hrow0 = (size_t)po + mbase;
  #pragma unroll
  for (int i = 0; i < 4; ++i) {
    #pragma unroll
    for (int rr = 0; rr < 4; ++rr) {
      int row = i * 16 + quad * 4 + rr;
      unsigned short* hr = h + (hrow0 + row) * FD + nbase;
      #pragma unroll
      for (int j = 0; j < 2; ++j) {
        int col = wn + j * 16 + lrow;
        float v = acc[i][j][rr] + b1[e * FD + nbase + col];
        hr[col] = f2bf(gelu_tanh(v));
      }
    }
  }
}

// ---------- GEMM2 (split-K x8): out[tok] += w * (h @ W2[e] + b2[e]) ----------
// XCD supertile: linear = sk + 8*(m + 16*n) + 1024*e
// -> all blocks of one (e, sk) group (16m x 8n) land on XCD sk: working set
//    A ~0.5MB + B 1MB fits the 4MB XCD L2; weights/h fetched once from HBM.
__global__ __launch_bounds__(256) void k_gemm2(
    const unsigned short* __restrict__ h, const unsigned short* __restrict__ w2t,
    const float* __restrict__ b2, const int* __restrict__ cnt,
    const int* __restrict__ idxl, const float* __restrict__ wtl, float* __restrict__ out) {
  const int l = blockIdx.x;
  const int sk = l & 7;
  const int m = (l >> 3) & 15;
  const int n = (l >> 7) & 7;
  const int e = l >> 10;

  const int c = cnt[e];
  const int mbase = m * 128;
  if (mbase >= c) return;
  const int nbase = n * 128;
  const int KC = FD / SK2;          // 512
  const int po = poff_of(cnt, e);
  const unsigned short* A = h + ((size_t)po + mbase) * FD + sk * KC;
  const unsigned short* B = w2t + ((size_t)e * HD + nbase) * FD + sk * KC;

  __shared__ unsigned short As[128 * 32];
  __shared__ unsigned short Bs[128 * 32];

  const int tid = threadIdx.x;
  const int wave = tid >> 6, lane = tid & 63;
  const int quad = lane >> 4, lrow = lane & 15;
  const int wm = (wave >> 1) * 64, wn = (wave & 1) * 64;

  floatx4 acc[4][4];
  #pragma unroll
  for (int i = 0; i < 4; ++i)
    #pragma unroll
    for (int j = 0; j < 4; ++j) acc[i][j] = (floatx4){0.f, 0.f, 0.f, 0.f};

  const int r0c = tid >> 2,          k0c = (tid & 3) * 8;
  const int r1c = (256 + tid) >> 2,  k1c = ((256 + tid) & 3) * 8;

  for (int kt = 0; kt < KC / 32; ++kt) {
    __syncthreads();
    const unsigned short* ga = A + kt * 32;
    const unsigned short* gb = B + kt * 32;
    gl2lds16(ga + (size_t)r0c * FD + k0c, As + (size_t)(wave * 64) * 8);
    gl2lds16(ga + (size_t)r1c * FD + k1c, As + (size_t)(256 + wave * 64) * 8);
    gl2lds16(gb + (size_t)r0c * FD + k0c, Bs + (size_t)(wave * 64) * 8);
    gl2lds16(gb + (size_t)r1c * FD + k1c, Bs + (size_t)(256 + wave * 64) * 8);
    __syncthreads();
    short8 aF[4], bF[4];
    #pragma unroll
    for (int i = 0; i < 4; ++i) aF[i] = *(const short8*)(As + (wm + i * 16 + lrow) * 32 + quad * 8);
    #pragma unroll
    for (int j = 0; j < 4; ++j) bF[j] = *(const short8*)(Bs + (wn + j * 16 + lrow) * 32 + quad * 8);
    #pragma unroll
    for (int i = 0; i < 4; ++i)
      #pragma unroll
      for (int j = 0; j < 4; ++j)
        acc[i][j] = __builtin_amdgcn_mfma_f32_16x16x32_bf16(aF[i], bF[j], acc[i][j], 0, 0, 0);
  }

  #pragma unroll
  for (int i = 0; i < 4; ++i) {
    #pragma unroll
    for (int rr = 0; rr < 4; ++rr) {
      int row = wm + i * 16 + quad * 4 + rr;
      int gr = mbase + row;
      if (gr < c) {
        int tok = idxl[e * N_TOK + gr];
        float wgt = wtl[e * N_TOK + gr];
        float* orow = out + (size_t)tok * HD + nbase;
        #pragma unroll
        for (int j = 0; j < 4; ++j) {
          int col = wn + j * 16 + lrow;
          float bias = (sk == 0) ? b2[e * HD + nbase + col] : 0.0f;
          atomicAdd(orow + col, wgt * (acc[i][j][rr] + bias));
        }
      }
    }
  }
}

// ---------- launch ----------
extern "C" void kernel_launch(void* const* d_in, const int* in_sizes, int n_in,
                              void* d_out, int out_size, void* d_ws, size_t ws_size,
                              hipStream_t stream) {
  const float* x  = (const float*)d_in[0];
  const int*   mp = (const int*)d_in[1];
  const float* wg = (const float*)d_in[2];
  const float* w1 = (const float*)d_in[3];
  const float* b1 = (const float*)d_in[4];
  const float* w2 = (const float*)d_in[5];
  const float* b2 = (const float*)d_in[6];
  float* out = (float*)d_out;
  char* ws = (char*)d_ws;

  float* p    = (float*)(ws + 0);
  int*   cnt  = (int*)(ws + 65536);
  int*   idxl = (int*)(ws + 66048);
  float* wtl  = (float*)(ws + 131584);
  unsigned short* w1t = (unsigned short*)(ws + 197120);
  unsigned short* w2t = (unsigned short*)(ws + 197120 + 67108864);
  unsigned short* xg  = (unsigned short*)(ws + 197120 + 2 * 67108864);
  unsigned short* h   = (unsigned short*)(ws + 197120 + 2 * 67108864 + 10485760);

  hipMemsetAsync(cnt, 0, 32, stream);
  hipMemsetAsync(d_out, 0, (size_t)out_size * 4, stream);

  k_gating<<<512, 256, 0, stream>>>(x, wg, p);
  k_softmax<<<NE, 256, 0, stream>>>(p);
  k_route<<<NE, 256, 0, stream>>>(mp, p, cnt, idxl, wtl);
  k_transcvt2<<<16384, 256, 0, stream>>>(w1, w1t, w2, w2t);
  k_gather<<<dim3(N_TOK, NE), 128, 0, stream>>>(x, cnt, idxl, xg);
  k_gemm1<<<8192, 256, 0, stream>>>(xg, w1t, b1, cnt, h);
  k_gemm2<<<8192, 256, 0, stream>>>(h, w2t, b2, cnt, idxl, wtl, out);
}

// Round 4
// 505.122 us; speedup vs baseline: 1.2331x; 1.1487x over previous
//
#include <hip/hip_runtime.h>

#define N_TOK 2048
#define HD    1024
#define FD    4096
#define NE    8

typedef __attribute__((ext_vector_type(8))) short short8;
typedef __attribute__((ext_vector_type(4))) float floatx4;

// ---------- helpers ----------
__device__ __forceinline__ unsigned short f2bf(float f) {
  unsigned int u = __float_as_uint(f);
  u += 0x7fffu + ((u >> 16) & 1u);   // RNE
  return (unsigned short)(u >> 16);
}

__device__ __forceinline__ void gl2lds16(const unsigned short* g, unsigned short* l) {
  __builtin_amdgcn_global_load_lds(
      (const __attribute__((address_space(1))) unsigned int*)g,
      (__attribute__((address_space(3))) unsigned int*)l, 16, 0, 0);
}

__device__ __forceinline__ float gelu_tanh(float x) {
  float t = 0.7978845608028654f * x * (1.0f + 0.044715f * x * x);
  return 0.5f * x * (1.0f + tanhf(t));
}

__device__ __forceinline__ int poff_of(const int* __restrict__ cnt, int e) {
  int o = 0;
  for (int i = 0; i < e; ++i) o += (cnt[i] + 127) & ~127;
  return o;
}

// ---------- gating ----------
__global__ void k_gating(const float* __restrict__ x, const float* __restrict__ wg,
                         float* __restrict__ p) {
  int wave = threadIdx.x >> 6;
  int lane = threadIdx.x & 63;
  int n = blockIdx.x * 4 + wave;
  const float4* xr = (const float4*)(x + (size_t)n * HD);
  float4 xv[4];
  #pragma unroll
  for (int i = 0; i < 4; ++i) xv[i] = xr[lane + i * 64];
  for (int e = 0; e < NE; ++e) {
    const float4* wr = (const float4*)(wg + (size_t)e * HD);
    float s = 0.f;
    #pragma unroll
    for (int i = 0; i < 4; ++i) {
      float4 w4 = wr[lane + i * 64];
      s += xv[i].x * w4.x + xv[i].y * w4.y + xv[i].z * w4.z + xv[i].w * w4.w;
    }
    for (int o = 32; o > 0; o >>= 1) s += __shfl_xor(s, o, 64);
    if (lane == 0) p[e * N_TOK + n] = s;
  }
}

// ---------- softmax over axis=0 ----------
__global__ void k_softmax(float* __restrict__ p) {
  int e = blockIdx.x;
  float* col = p + e * N_TOK;
  __shared__ float red[256];
  int t = threadIdx.x;
  float m = -1e30f;
  for (int i = t; i < N_TOK; i += 256) m = fmaxf(m, col[i]);
  red[t] = m; __syncthreads();
  for (int s = 128; s > 0; s >>= 1) { if (t < s) red[t] = fmaxf(red[t], red[t + s]); __syncthreads(); }
  m = red[0]; __syncthreads();
  float sum = 0.f;
  for (int i = t; i < N_TOK; i += 256) { float v = expf(col[i] - m); col[i] = v; sum += v; }
  red[t] = sum; __syncthreads();
  for (int s = 128; s > 0; s >>= 1) { if (t < s) red[t] += red[t + s]; __syncthreads(); }
  float inv = 1.0f / red[0];
  for (int i = t; i < N_TOK; i += 256) col[i] *= inv;
}

// ---------- routing: arena lists + token-indexed (expert,slot,weight) ----------
__global__ void k_route(const int* __restrict__ mp, const float* __restrict__ p,
                        int* __restrict__ cnt, int* __restrict__ idxl,
                        int* __restrict__ tke, int* __restrict__ tks, float* __restrict__ tkw) {
  int n = blockIdx.x * 256 + threadIdx.x;
  if (n >= N_TOK) return;
  int m0 = mp[n * 2 + 0], m1 = mp[n * 2 + 1];
  if (m0 == m1) {
    int s = atomicAdd(&cnt[m0], 1);
    idxl[m0 * N_TOK + s] = n;
    tke[n * 2] = m0; tks[n * 2] = s; tkw[n * 2] = 1.0f;
    tke[n * 2 + 1] = m0; tks[n * 2 + 1] = s; tkw[n * 2 + 1] = 0.0f;
  } else {
    float p0 = p[m0 * N_TOK + n], p1 = p[m1 * N_TOK + n];
    float inv = 1.0f / (p0 + p1);
    int s0 = atomicAdd(&cnt[m0], 1);
    idxl[m0 * N_TOK + s0] = n;
    tke[n * 2] = m0; tks[n * 2] = s0; tkw[n * 2] = p0 * inv;
    int s1 = atomicAdd(&cnt[m1], 1);
    idxl[m1 * N_TOK + s1] = n;
    tke[n * 2 + 1] = m1; tks[n * 2 + 1] = s1; tkw[n * 2 + 1] = p1 * inv;
  }
}

// ---------- gather x rows -> bf16 arena ----------
__global__ void k_gather(const float* __restrict__ x, const int* __restrict__ cnt,
                         const int* __restrict__ idxl, unsigned short* __restrict__ xg) {
  int e = blockIdx.y;
  int r = blockIdx.x;
  int c = cnt[e];
  int pc = (c + 127) & ~127;
  if (r >= pc) return;
  unsigned short* dst = xg + ((size_t)poff_of(cnt, e) + r) * HD;
  int t = threadIdx.x;
  union { unsigned short us[8]; uint4 v; } o;
  if (r < c) {
    const float* src = x + (size_t)idxl[e * N_TOK + r] * HD;
    float4 f0 = ((const float4*)src)[t * 2];
    float4 f1 = ((const float4*)src)[t * 2 + 1];
    o.us[0] = f2bf(f0.x); o.us[1] = f2bf(f0.y); o.us[2] = f2bf(f0.z); o.us[3] = f2bf(f0.w);
    o.us[4] = f2bf(f1.x); o.us[5] = f2bf(f1.y); o.us[6] = f2bf(f1.z); o.us[7] = f2bf(f1.w);
  } else {
    o.v.x = 0u; o.v.y = 0u; o.v.z = 0u; o.v.w = 0u;
  }
  ((uint4*)dst)[t] = o.v;
}

// ---------- merged transpose + fp32->bf16 for W1 and W2 ----------
__global__ __launch_bounds__(256) void k_transcvt2(const float* __restrict__ w1,
                                                   unsigned short* __restrict__ w1t,
                                                   const float* __restrict__ w2,
                                                   unsigned short* __restrict__ w2t) {
  __shared__ float tile[64][65];
  int l = blockIdx.x;
  const float* src; unsigned short* dst; int rows, cols, bx, by, e;
  if (l < 8192) {        // W1: rows=HD, cols=FD
    src = w1; dst = w1t; rows = HD; cols = FD;
    bx = l & 63; by = (l >> 6) & 15; e = l >> 10;
  } else {               // W2: rows=FD, cols=HD
    int l2 = l - 8192;
    src = w2; dst = w2t; rows = FD; cols = HD;
    bx = l2 & 15; by = (l2 >> 4) & 63; e = l2 >> 10;
  }
  const size_t base = (size_t)e * rows * cols;
  int c0 = bx * 64, r0 = by * 64;
  int t = threadIdx.x;
  int lr = t >> 4;
  int lc = (t & 15) * 4;
  #pragma unroll
  for (int i = 0; i < 64; i += 16) {
    float4 v = *(const float4*)(src + base + (size_t)(r0 + lr + i) * cols + c0 + lc);
    tile[lr + i][lc] = v.x; tile[lr + i][lc + 1] = v.y;
    tile[lr + i][lc + 2] = v.z; tile[lr + i][lc + 3] = v.w;
  }
  __syncthreads();
  int oc = t >> 2;
  int rseg = (t & 3) * 16;
  union { unsigned short us[16]; uint4 v[2]; } o;
  #pragma unroll
  for (int i = 0; i < 16; ++i) o.us[i] = f2bf(tile[rseg + i][oc]);
  unsigned short* d = dst + base + (size_t)(c0 + oc) * rows + r0 + rseg;
  ((uint4*)d)[0] = o.v[0];
  ((uint4*)d)[1] = o.v[1];
}

// ---------- GEMM1: h = gelu(xg @ W1[e] + b1[e])  (K=1024, tile 64x128) ----------
__global__ __launch_bounds__(256) void k_gemm1(
    const unsigned short* __restrict__ xg, const unsigned short* __restrict__ w1t,
    const float* __restrict__ b1, const int* __restrict__ cnt,
    unsigned short* __restrict__ h) {
  const int l = blockIdx.x;
  const int r = l & 7;
  const int m = (l >> 3) & 31;
  const int q = l >> 8;
  const int e = q >> 2;
  const int n = ((q & 3) << 3) | r;

  const int c = cnt[e];
  const int mbase = m * 64;
  if (mbase >= c) return;
  const int nbase = n * 128;
  const int po = poff_of(cnt, e);
  const unsigned short* A = xg + ((size_t)po + mbase) * HD;
  const unsigned short* B = w1t + ((size_t)e * FD + nbase) * HD;

  __shared__ unsigned short As[64 * 32];
  __shared__ unsigned short Bs[128 * 32];

  const int tid = threadIdx.x;
  const int wave = tid >> 6, lane = tid & 63;
  const int quad = lane >> 4, lrow = lane & 15;
  const int wn = wave * 32;

  floatx4 acc[4][2];
  #pragma unroll
  for (int i = 0; i < 4; ++i)
    #pragma unroll
    for (int j = 0; j < 2; ++j) acc[i][j] = (floatx4){0.f, 0.f, 0.f, 0.f};

  const int rA = tid >> 2, kA = (tid & 3) * 8;
  const int rB0 = tid >> 2, kB0 = (tid & 3) * 8;
  const int rB1 = (256 + tid) >> 2, kB1 = ((256 + tid) & 3) * 8;

  for (int kt = 0; kt < HD / 32; ++kt) {
    __syncthreads();
    const unsigned short* ga = A + kt * 32;
    const unsigned short* gb = B + kt * 32;
    gl2lds16(ga + (size_t)rA * HD + kA, As + (size_t)(wave * 64) * 8);
    gl2lds16(gb + (size_t)rB0 * HD + kB0, Bs + (size_t)(wave * 64) * 8);
    gl2lds16(gb + (size_t)rB1 * HD + kB1, Bs + (size_t)(256 + wave * 64) * 8);
    __syncthreads();
    short8 aF[4], bF[2];
    #pragma unroll
    for (int i = 0; i < 4; ++i) aF[i] = *(const short8*)(As + (i * 16 + lrow) * 32 + quad * 8);
    #pragma unroll
    for (int j = 0; j < 2; ++j) bF[j] = *(const short8*)(Bs + (wn + j * 16 + lrow) * 32 + quad * 8);
    #pragma unroll
    for (int i = 0; i < 4; ++i)
      #pragma unroll
      for (int j = 0; j < 2; ++j)
        acc[i][j] = __builtin_amdgcn_mfma_f32_16x16x32_bf16(aF[i], bF[j], acc[i][j], 0, 0, 0);
  }

  const size_t hrow0 = (size_t)po + mbase;
  #pragma unroll
  for (int i = 0; i < 4; ++i) {
    #pragma unroll
    for (int rr = 0; rr < 4; ++rr) {
      int row = i * 16 + quad * 4 + rr;
      unsigned short* hr = h + (hrow0 + row) * FD + nbase;
      #pragma unroll
      for (int j = 0; j < 2; ++j) {
        int col = wn + j * 16 + lrow;
        float v = acc[i][j][rr] + b1[e * FD + nbase + col];
        hr[col] = f2bf(gelu_tanh(v));
      }
    }
  }
}

// ---------- GEMM2: ya = h @ W2[e]  (K=4096 full, tile 64x64, BK=64, no atomics) ----------
// Global padded-row space; each block owns its 64x64 output tile, stores bf16.
__global__ __launch_bounds__(256) void k_gemm2(
    const unsigned short* __restrict__ h, const unsigned short* __restrict__ w2t,
    const int* __restrict__ cnt, unsigned short* __restrict__ ya) {
  const int l = blockIdx.x;
  const int nt = l & 15;
  const int mt = l >> 4;
  const int mbase = mt * 64;
  const int nbase = nt * 64;

  // expert lookup over padded row space
  int e = -1, po = 0, ce = 0;
  {
    int o = 0;
    #pragma unroll
    for (int i = 0; i < NE; ++i) {
      int ci = cnt[i];
      int pc = (ci + 127) & ~127;
      if (mbase >= o && mbase < o + pc) { e = i; po = o; ce = ci; }
      o += pc;
    }
  }
  if (e < 0) return;                 // beyond padded total
  if (mbase - po >= ce) return;      // pure pad tile

  const unsigned short* A = h + (size_t)mbase * FD;
  const unsigned short* B = w2t + ((size_t)e * HD + nbase) * FD;

  __shared__ unsigned short As[64 * 64];
  __shared__ unsigned short Bs[64 * 64];

  const int tid = threadIdx.x;
  const int wave = tid >> 6, lane = tid & 63;
  const int quad = lane >> 4, lrow = lane & 15;
  const int wm = (wave >> 1) * 32, wn = (wave & 1) * 32;

  floatx4 acc[2][2];
  #pragma unroll
  for (int i = 0; i < 2; ++i)
    #pragma unroll
    for (int j = 0; j < 2; ++j) acc[i][j] = (floatx4){0.f, 0.f, 0.f, 0.f};

  // staging slots: 512 slots of 16B per buffer; slot s -> row s>>3, k (s&7)*8
  const int s0 = tid,        r0 = s0 >> 3, k0 = (s0 & 7) * 8;
  const int s1 = 256 + tid,  r1 = s1 >> 3, k1 = (s1 & 7) * 8;

  for (int kt = 0; kt < FD / 64; ++kt) {
    __syncthreads();
    const unsigned short* ga = A + kt * 64;
    const unsigned short* gb = B + kt * 64;
    gl2lds16(ga + (size_t)r0 * FD + k0, As + (size_t)(wave * 64) * 8);
    gl2lds16(ga + (size_t)r1 * FD + k1, As + (size_t)(256 + wave * 64) * 8);
    gl2lds16(gb + (size_t)r0 * FD + k0, Bs + (size_t)(wave * 64) * 8);
    gl2lds16(gb + (size_t)r1 * FD + k1, Bs + (size_t)(256 + wave * 64) * 8);
    __syncthreads();
    #pragma unroll
    for (int c = 0; c < 2; ++c) {
      short8 aF[2], bF[2];
      #pragma unroll
      for (int i = 0; i < 2; ++i) aF[i] = *(const short8*)(As + (wm + i * 16 + lrow) * 64 + c * 32 + quad * 8);
      #pragma unroll
      for (int j = 0; j < 2; ++j) bF[j] = *(const short8*)(Bs + (wn + j * 16 + lrow) * 64 + c * 32 + quad * 8);
      #pragma unroll
      for (int i = 0; i < 2; ++i)
        #pragma unroll
        for (int j = 0; j < 2; ++j)
          acc[i][j] = __builtin_amdgcn_mfma_f32_16x16x32_bf16(aF[i], bF[j], acc[i][j], 0, 0, 0);
    }
  }

  #pragma unroll
  for (int i = 0; i < 2; ++i) {
    #pragma unroll
    for (int rr = 0; rr < 4; ++rr) {
      int row = mbase + wm + i * 16 + quad * 4 + rr;
      unsigned short* yr = ya + (size_t)row * HD + nbase;
      #pragma unroll
      for (int j = 0; j < 2; ++j) {
        int col = wn + j * 16 + lrow;
        yr[col] = f2bf(acc[i][j][rr]);
      }
    }
  }
}

// ---------- combine: out[n] = sum_k w_k * (ya[pos_k] + b2[e_k]) ----------
__global__ __launch_bounds__(256) void k_combine(
    const unsigned short* __restrict__ ya, const float* __restrict__ b2,
    const int* __restrict__ cnt, const int* __restrict__ tke,
    const int* __restrict__ tks, const float* __restrict__ tkw,
    float* __restrict__ out) {
  int n = blockIdx.x;
  int e0 = tke[n * 2], e1 = tke[n * 2 + 1];
  int p0 = poff_of(cnt, e0) + tks[n * 2];
  int p1 = poff_of(cnt, e1) + tks[n * 2 + 1];
  float w0 = tkw[n * 2], w1 = tkw[n * 2 + 1];
  int c = threadIdx.x * 4;
  union { unsigned short us[4]; ushort2 u2[2]; unsigned long long ll; } y0, y1;
  y0.ll = *(const unsigned long long*)(ya + (size_t)p0 * HD + c);
  y1.ll = *(const unsigned long long*)(ya + (size_t)p1 * HD + c);
  float4 bb0 = *(const float4*)(b2 + (size_t)e0 * HD + c);
  float4 bb1 = *(const float4*)(b2 + (size_t)e1 * HD + c);
  float4 o;
  o.x = w0 * (__uint_as_float((unsigned)y0.us[0] << 16) + bb0.x) + w1 * (__uint_as_float((unsigned)y1.us[0] << 16) + bb1.x);
  o.y = w0 * (__uint_as_float((unsigned)y0.us[1] << 16) + bb0.y) + w1 * (__uint_as_float((unsigned)y1.us[1] << 16) + bb1.y);
  o.z = w0 * (__uint_as_float((unsigned)y0.us[2] << 16) + bb0.z) + w1 * (__uint_as_float((unsigned)y1.us[2] << 16) + bb1.z);
  o.w = w0 * (__uint_as_float((unsigned)y0.us[3] << 16) + bb0.w) + w1 * (__uint_as_float((unsigned)y1.us[3] << 16) + bb1.w);
  *(float4*)(out + (size_t)n * HD + c) = o;
}

// ---------- launch ----------
extern "C" void kernel_launch(void* const* d_in, const int* in_sizes, int n_in,
                              void* d_out, int out_size, void* d_ws, size_t ws_size,
                              hipStream_t stream) {
  const float* x  = (const float*)d_in[0];
  const int*   mp = (const int*)d_in[1];
  const float* wg = (const float*)d_in[2];
  const float* w1 = (const float*)d_in[3];
  const float* b1 = (const float*)d_in[4];
  const float* w2 = (const float*)d_in[5];
  const float* b2 = (const float*)d_in[6];
  float* out = (float*)d_out;
  char* ws = (char*)d_ws;

  float* p    = (float*)(ws + 0);            // 65536
  int*   cnt  = (int*)(ws + 65536);          // 32
  int*   idxl = (int*)(ws + 66048);          // 65536
  int*   tke  = (int*)(ws + 131584);         // 16384
  int*   tks  = (int*)(ws + 147968);         // 16384
  float* tkw  = (float*)(ws + 164352);       // 16384
  size_t off = 180736;
  unsigned short* w1t = (unsigned short*)(ws + off);  off += 67108864;
  unsigned short* w2t = (unsigned short*)(ws + off);  off += 67108864;
  unsigned short* xg  = (unsigned short*)(ws + off);  off += 10485760;   // 5120*1024*2
  unsigned short* h   = (unsigned short*)(ws + off);  off += 41943040;   // 5120*4096*2
  unsigned short* ya  = (unsigned short*)(ws + off);  off += 10485760;   // 5120*1024*2

  hipMemsetAsync(cnt, 0, 32, stream);

  k_gating<<<512, 256, 0, stream>>>(x, wg, p);
  k_softmax<<<NE, 256, 0, stream>>>(p);
  k_route<<<NE, 256, 0, stream>>>(mp, p, cnt, idxl, tke, tks, tkw);
  k_transcvt2<<<16384, 256, 0, stream>>>(w1, w1t, w2, w2t);
  k_gather<<<dim3(N_TOK, NE), 128, 0, stream>>>(x, cnt, idxl, xg);
  k_gemm1<<<8192, 256, 0, stream>>>(xg, w1t, b1, cnt, h);
  k_gemm2<<<80 * 16, 256, 0, stream>>>(h, w2t, cnt, ya);
  k_combine<<<N_TOK, 256, 0, stream>>>(ya, b2, cnt, tke, tks, tkw, out);
}